// Round 6
// baseline (206.360 us; speedup 1.0000x reference)
//
#include <hip/hip_runtime.h>

#define HH 64
#define WW 64
#define S  68          // padded LDS row stride (floats)
#define PH 66          // padded rows (1-px zero frame)
#define NLQ 10
#define NR 8           // rows per thread (512 threads = 8 waves = 2/SIMD)

// One block per image (grid=256 = 1 block/CU). Thread t: column x=t&63, rows
// y0..y0+7.
//
// History of the weight-residency war (90 uniform transition weights):
//  R1  (110us): LDS-staged -> AGPR demotion -> 720 v_accvgpr_read/step.
//  R9  (940us): asm "a"-pinning -> SCRATCH. Never.
//  R10 (122us): per-step LDS re-read -> LDS pipe binds (8 waves share it).
//  R11 (148us): per-step global re-read -> barrier blocks hoisting, lgkmcnt
//               serialization.
//  R12 (103us): f32x2 pk pairs -> vectors of uniform values materialize in
//               VGPRs -> AGPR demotion again; VALUBusy 60% (=latency+bloat).
//  R13 (this): SCALAR floats + readfirstlane -> forced SGPR residency.
//      v_fma_f32 takes one SGPR operand: weights cost ZERO VALU/LDS ops in
//      the K-loop and SGPRs survive barriers. 90 weights + ~8 overhead fits
//      the 102-SGPR file. q0r stays plain local (mostly arch VGPR at the
//      128 budget; any demotion = 1 cheap accvgpr read/use).
__global__ __launch_bounds__(512)
__attribute__((amdgpu_waves_per_eu(2, 2)))
void vin_fused(
    const float* __restrict__ X,    // [B,2,64,64]
    const float* __restrict__ Wh,   // [150,2,3,3]
    const float* __restrict__ bh,   // [150]
    const float* __restrict__ Wr,   // [150]
    const float* __restrict__ Wq,   // [10,1,3,3]
    const float* __restrict__ wtr,  // [10,1,3,3] transition
    const float* __restrict__ Wc,   // [4096]
    const float* __restrict__ bc,   // [1]
    float* __restrict__ out)        // [256 critic] ++ [256*40960 q]
{
  __shared__ float vb[2][PH * S];
  __shared__ float rb[PH * S];
  __shared__ float Wef[19];
  __shared__ float Wpart[152];
  __shared__ float red[8];

  const int b  = blockIdx.x;
  const int t  = threadIdx.x;
  const int x  = t & 63;
  const int yg = t >> 6;
  const int y0 = yg * NR;
  const int base0 = y0 * S + x;   // top-left of 3x3 window for row y0 (padded)

  // ---- zero LDS (frames must be 0; interiors overwritten) ----
  {
    float* vbf = &vb[0][0];
    for (int i = t; i < 2 * PH * S; i += 512) vbf[i] = 0.f;
    for (int i = t; i < PH * S; i += 512) rb[i] = 0.f;
  }
  __syncthreads();

  // ---- stage X into vb interiors; collapse 150-ch conv to Wef[19] ----
  const float* Xb = X + (size_t)b * (2 * HH * WW);
  for (int i = t; i < HH * WW; i += 512) {
    const int yy = i >> 6, xx = i & 63;
    vb[0][(yy + 1) * S + xx + 1] = Xb[i];
    vb[1][(yy + 1) * S + xx + 1] = Xb[HH * WW + i];
  }
  if (t < 152) {                       // parallel collapse: 19 outputs x 8 parts
    const int i = t >> 3, part = t & 7;
    float s = 0.f;
    if (i < 18) {
      for (int c = part; c < 150; c += 8) s += Wr[c] * Wh[c * 18 + i];
    } else {
      for (int c = part; c < 150; c += 8) s += Wr[c] * bh[c];
    }
    Wpart[t] = s;
  }
  __syncthreads();
  if (t < 19) {
    float s = 0.f;
#pragma unroll
    for (int k = 0; k < 8; ++k) s += Wpart[t * 8 + k];
    Wef[t] = s;
  }
  __syncthreads();

  // ---- r = conv(X, Weff, pad=1) + beff -> rb ----
  {
    float We[19];
#pragma unroll
    for (int i = 0; i < 19; ++i) We[i] = Wef[i];
#pragma unroll
    for (int j = 0; j < NR; ++j) {
      const int tb = base0 + j * S;
      float s = We[18];
#pragma unroll
      for (int dy = 0; dy < 3; ++dy)
#pragma unroll
        for (int dx = 0; dx < 3; ++dx) {
          const int idx = tb + dy * S + dx;
          s = fmaf(vb[0][idx], We[dy * 3 + dx], s);
          s = fmaf(vb[1][idx], We[9 + dy * 3 + dx], s);
        }
      rb[tb + S + 1] = s;
    }
  }
  __syncthreads();

  // ---- transition weights -> SGPRs, ONCE, before the K-loop ----
  // readfirstlane forces SREG class; values are uniform so it's an identity.
  float wt[90];
#pragma unroll
  for (int i = 0; i < 90; ++i)
    wt[i] = __int_as_float(__builtin_amdgcn_readfirstlane(__float_as_int(wtr[i])));

  // ---- q0 = conv(r, Wq, pad=1) -> q0r regs; v_init = max_l q0 -> vb[0] ----
  // j-outer / tap-middle / l-inner: rb read once per (j,tap) = 72 LDS reads.
  float q0r[NR][NLQ];
  {
    float wq[90];
#pragma unroll
    for (int i = 0; i < 90; ++i)
      wq[i] = __int_as_float(__builtin_amdgcn_readfirstlane(__float_as_int(Wq[i])));
#pragma unroll
    for (int j = 0; j < NR; ++j) {
      const int a = base0 + j * S;
      float acc[NLQ];
#pragma unroll
      for (int l = 0; l < NLQ; ++l) acc[l] = 0.f;
#pragma unroll
      for (int dy = 0; dy < 3; ++dy)
#pragma unroll
        for (int dx = 0; dx < 3; ++dx) {
          const int k = dy * 3 + dx;
          const float v = rb[a + dy * S + dx];
#pragma unroll
          for (int l = 0; l < NLQ; ++l) acc[l] = fmaf(wq[l * 9 + k], v, acc[l]);
        }
      float m = acc[0];
#pragma unroll
      for (int l = 0; l < NLQ; ++l) {
        q0r[j][l] = acc[l];
        if (l > 0) m = fmaxf(m, acc[l]);
      }
      vb[0][base0 + (j + 1) * S + 1] = m;
    }
  }
  __syncthreads();

  // ---- K-loop: q = q0 + conv(v, w); v = max_ch(q) ----
  // Weights in SGPRs (one scalar operand per v_fma). Window rows in 30 VGPRs.
  auto step = [&](const float* __restrict__ vin, float* __restrict__ vout) {
    float win[NR + 2][3];
#pragma unroll
    for (int rr = 0; rr < NR + 2; ++rr) {
      const int a = base0 + rr * S;
      win[rr][0] = vin[a];
      win[rr][1] = vin[a + 1];
      win[rr][2] = vin[a + 2];
    }
#pragma unroll
    for (int j = 0; j < NR; ++j) {
      float m;
#pragma unroll
      for (int l = 0; l < NLQ; ++l) {
        float s = q0r[j][l];
        s = fmaf(wt[l * 9 + 0], win[j][0],     s);
        s = fmaf(wt[l * 9 + 1], win[j][1],     s);
        s = fmaf(wt[l * 9 + 2], win[j][2],     s);
        s = fmaf(wt[l * 9 + 3], win[j + 1][0], s);
        s = fmaf(wt[l * 9 + 4], win[j + 1][1], s);
        s = fmaf(wt[l * 9 + 5], win[j + 1][2], s);
        s = fmaf(wt[l * 9 + 6], win[j + 2][0], s);
        s = fmaf(wt[l * 9 + 7], win[j + 2][1], s);
        s = fmaf(wt[l * 9 + 8], win[j + 2][2], s);
        m = (l == 0) ? s : fmaxf(m, s);
      }
      vout[base0 + (j + 1) * S + 1] = m;
    }
    __syncthreads();
  };

#pragma unroll 1
  for (int s2 = 0; s2 < 19; ++s2) { step(vb[0], vb[1]); step(vb[1], vb[0]); }
  step(vb[0], vb[1]);   // it = 38: reads vb[0], writes vb[1]

  // ---- final iteration (it=39): emit q + critic dot ----
  float wcv[NR];
#pragma unroll
  for (int j = 0; j < NR; ++j) wcv[j] = Wc[(y0 + j) * WW + x];

  float* qo = out + 256 + (size_t)b * (NLQ * HH * WW) + y0 * WW + x;
  float acc_c = 0.f;
  {
    const float* vin = vb[1];
    float win[NR + 2][3];
#pragma unroll
    for (int rr = 0; rr < NR + 2; ++rr) {
      const int a = base0 + rr * S;
      win[rr][0] = vin[a];
      win[rr][1] = vin[a + 1];
      win[rr][2] = vin[a + 2];
    }
#pragma unroll
    for (int j = 0; j < NR; ++j) {
      float m;
#pragma unroll
      for (int l = 0; l < NLQ; ++l) {
        float s = q0r[j][l];
        s = fmaf(wt[l * 9 + 0], win[j][0],     s);
        s = fmaf(wt[l * 9 + 1], win[j][1],     s);
        s = fmaf(wt[l * 9 + 2], win[j][2],     s);
        s = fmaf(wt[l * 9 + 3], win[j + 1][0], s);
        s = fmaf(wt[l * 9 + 4], win[j + 1][1], s);
        s = fmaf(wt[l * 9 + 5], win[j + 1][2], s);
        s = fmaf(wt[l * 9 + 6], win[j + 2][0], s);
        s = fmaf(wt[l * 9 + 7], win[j + 2][1], s);
        s = fmaf(wt[l * 9 + 8], win[j + 2][2], s);
        qo[l * (HH * WW) + j * WW] = s;
        m = (l == 0) ? s : fmaxf(m, s);
      }
      acc_c = fmaf(m, wcv[j], acc_c);
    }
  }

  // ---- block-reduce critic ----
#pragma unroll
  for (int off = 32; off > 0; off >>= 1) acc_c += __shfl_down(acc_c, off);
  if (x == 0) red[yg] = acc_c;
  __syncthreads();
  if (t == 0) {
    float s = bc[0];
#pragma unroll
    for (int i = 0; i < 8; ++i) s += red[i];
    out[b] = s;
  }
}

extern "C" void kernel_launch(void* const* d_in, const int* in_sizes, int n_in,
                              void* d_out, int out_size, void* d_ws, size_t ws_size,
                              hipStream_t stream) {
  (void)n_in; (void)out_size; (void)d_ws; (void)ws_size;
  const float* X   = (const float*)d_in[0];
  const float* Wh  = (const float*)d_in[1];
  const float* bh  = (const float*)d_in[2];
  const float* Wr  = (const float*)d_in[3];
  const float* Wq  = (const float*)d_in[4];
  const float* wtr = (const float*)d_in[5];
  const float* Wc  = (const float*)d_in[6];
  const float* bc  = (const float*)d_in[7];
  float* out = (float*)d_out;

  const int B = in_sizes[0] / (2 * HH * WW);   // 256
  vin_fused<<<B, 512, 0, stream>>>(X, Wh, bh, Wr, Wq, wtr, Wc, bc, out);
}